// Round 3
// baseline (125.367 us; speedup 1.0000x reference)
//
#include <hip/hip_runtime.h>

#define LOG2E 1.4426950408889634f

typedef __attribute__((ext_vector_type(8))) short short8;
typedef __attribute__((ext_vector_type(16))) float f32x16;

__device__ __forceinline__ unsigned short f2bf(float f) {
  unsigned int u = __float_as_uint(f);
  u = (u + 0x7fffu + ((u >> 16) & 1u)) >> 16;   // RNE, finite inputs only
  return (unsigned short)u;
}

// ---------------------------------------------------------------------------
// Kernel 1: f = X @ W^T + b  (fp32 SGEMM, 128x128 tile, 8x8/thread)
// Emits: ft (bf16, layout [b][n/16][h][c][n%16]) and s_src/s_dst ([b][h][n],
// f32, PRE-SCALED by log2(e) so k2 can use raw v_exp_f32).
// ---------------------------------------------------------------------------
__global__ __launch_bounds__(256) void gat_k1(
    const float* __restrict__ X, const float* __restrict__ W,
    const float* __restrict__ bias, const float* __restrict__ a,
    unsigned short* __restrict__ ft, float* __restrict__ ssrc,
    float* __restrict__ sdst)
{
  __shared__ float Xs[8][128];
  __shared__ float Ws[8][128];
  const int tid = threadIdx.x;
  const int tx = tid & 15, ty = tid >> 4;
  const int m0 = blockIdx.x * 128;
  const int c0 = blockIdx.y * 128;

  float acc[8][8];
#pragma unroll
  for (int r = 0; r < 8; ++r)
#pragma unroll
    for (int j = 0; j < 8; ++j) acc[r][j] = 0.f;

  const int lrow = tid >> 1;
  const int kk0 = (tid & 1) * 4;
  const float* Xp = X + (size_t)(m0 + lrow) * 256 + kk0;
  const float* Wp = W + (size_t)(c0 + lrow) * 256 + kk0;

  for (int kc = 0; kc < 256; kc += 8) {
    float4 xv = *(const float4*)(Xp + kc);
    float4 wv = *(const float4*)(Wp + kc);
    __syncthreads();
    Xs[kk0 + 0][lrow] = xv.x; Xs[kk0 + 1][lrow] = xv.y;
    Xs[kk0 + 2][lrow] = xv.z; Xs[kk0 + 3][lrow] = xv.w;
    Ws[kk0 + 0][lrow] = wv.x; Ws[kk0 + 1][lrow] = wv.y;
    Ws[kk0 + 2][lrow] = wv.z; Ws[kk0 + 3][lrow] = wv.w;
    __syncthreads();
#pragma unroll
    for (int kk = 0; kk < 8; ++kk) {
      float av[8], wv8[8];
#pragma unroll
      for (int r = 0; r < 8; ++r) av[r] = Xs[kk][ty * 8 + r];
#pragma unroll
      for (int j = 0; j < 8; ++j) wv8[j] = Ws[kk][tx * 8 + j];
#pragma unroll
      for (int r = 0; r < 8; ++r)
#pragma unroll
        for (int j = 0; j < 8; ++j) acc[r][j] = fmaf(av[r], wv8[j], acc[r][j]);
    }
  }

  const int b = m0 >> 11;
  const int nloc0 = (m0 & 2047) + ty * 8;
  const int cg0 = c0 + tx * 8;
  const int h = cg0 >> 6;
  const int cb = cg0 & 63;

  float bv[8], av_s[8], av_d[8];
#pragma unroll
  for (int j = 0; j < 8; ++j) {
    bv[j]   = bias[cg0 + j];
    av_s[j] = a[h * 128 + cb + j];
    av_d[j] = a[h * 128 + 64 + cb + j];
  }
#pragma unroll
  for (int r = 0; r < 8; ++r)
#pragma unroll
    for (int j = 0; j < 8; ++j) acc[r][j] += bv[j];

  const int jt = nloc0 >> 4;
  const int ni = nloc0 & 15;
#pragma unroll
  for (int j = 0; j < 8; ++j) {
    unsigned int u[4];
#pragma unroll
    for (int q = 0; q < 4; ++q) {
      unsigned int lo = f2bf(acc[2 * q + 0][j]);
      unsigned int hi = f2bf(acc[2 * q + 1][j]);
      u[q] = lo | (hi << 16);
    }
    size_t off = ((((size_t)b * 128 + jt) * 4 + h) * 64 + (cb + j)) * 16 + ni;
    *(uint4*)(ft + off) = make_uint4(u[0], u[1], u[2], u[3]);
  }

  float sp[8], dp[8];
#pragma unroll
  for (int r = 0; r < 8; ++r) {
    float s = 0.f, d = 0.f;
#pragma unroll
    for (int j = 0; j < 8; ++j) {
      s = fmaf(acc[r][j], av_s[j], s);
      d = fmaf(acc[r][j], av_d[j], d);
    }
    sp[r] = s; dp[r] = d;
  }
#pragma unroll
  for (int off = 1; off < 8; off <<= 1) {
#pragma unroll
    for (int r = 0; r < 8; ++r) {
      sp[r] += __shfl_xor(sp[r], off);
      dp[r] += __shfl_xor(dp[r], off);
    }
  }
  if ((tx & 7) == 0) {
    float* sb = ssrc + ((size_t)b * 4 + h) * 2048 + nloc0;
    float* db = sdst + ((size_t)b * 4 + h) * 2048 + nloc0;
#pragma unroll
    for (int r = 0; r < 8; ++r) { sb[r] = sp[r] * LOG2E; db[r] = dp[r] * LOG2E; }
  }
}

// ---------------------------------------------------------------------------
// Kernel 2: fused mask + leaky-relu + softmax + PV (bf16 MFMA 32x32x16)
// Grid 512 blocks (b = idx&7 XCD-pinned, itile = idx>>3, 32 i-rows).
// 512 thr = 8 waves = (head h, j-parity p). NO LDS staging of ft/adj:
// both MFMA operand sides are built directly from global (L2/L3-resident)
// into registers. Zero barriers in the 64-step main loop; 2-deep register
// double-buffer (named A/B) hides L2/L3 latency under VALU work.
// ---------------------------------------------------------------------------
__global__ __launch_bounds__(512, 4) void gat_k2(
    const int* __restrict__ adj, const unsigned short* __restrict__ ft,
    const float* __restrict__ ssrc, const float* __restrict__ sdst,
    float* __restrict__ out)
{
  __shared__ __align__(16) unsigned char lds[33280];   // sd (32KB) / ep+el reuse
  float* sd = (float*)lds;                             // [4][2048] f32

  const int tid = threadIdx.x;
  const int b = blockIdx.x & 7;
  const int itile = blockIdx.x >> 3;     // 0..63
  const int i0 = itile * 32;
  const int w = tid >> 6;
  const int h = w >> 1;
  const int p = w & 1;
  const int lane = tid & 63;
  const int l31 = lane & 31;
  const int kh = lane >> 5;

  // ---- stage s_dst once (32 KB, contiguous) ----
  {
    const float4* src = (const float4*)(sdst + (size_t)b * 4 * 2048);
    float4* dst = (float4*)sd;
#pragma unroll
    for (int q = 0; q < 4; ++q) dst[tid + q * 512] = src[tid + q * 512];
  }
  const float si = ssrc[((size_t)b * 4 + h) * 2048 + i0 + l31];

  // per-lane global bases
  // ft: (((b*128 + jt)*4 + h)*64 + c)*16 + ni ; jt = 2s+p, ni = kh*8, c = l31
  const unsigned short* ftb =
      ft + ((((size_t)b * 128 + p) * 4 + h) * 64 + l31) * 16 + kh * 8;
  const int* adjp = adj + (size_t)b * 2048 * 2048 +
                    (size_t)(i0 + l31) * 2048 + p * 16 + kh * 8;
  const float* sdh = sd + h * 2048 + p * 16 + kh * 8;

  f32x16 acc0, acc1;
#pragma unroll
  for (int q = 0; q < 16; ++q) { acc0[q] = 0.f; acc1[q] = 0.f; }
  float lsum = 0.f;

  __syncthreads();

  struct Pref { uint4 fb0, fb1; int4 a0, a1; };

  auto LOADS = [&](int s, Pref& P) {
    const unsigned short* fp = ftb + (size_t)s * 8192;
    P.fb0 = *(const uint4*)fp;
    P.fb1 = *(const uint4*)(fp + 512);
    const int* ap = adjp + s * 32;
    P.a0 = *(const int4*)ap;
    P.a1 = *(const int4*)(ap + 4);
  };

  auto COMP = [&](int s, const Pref& P) {
    const float* tp = sdh + s * 32;
    float4 t0 = *(const float4*)tp;
    float4 t1 = *(const float4*)(tp + 4);
    float tj[8] = {t0.x, t0.y, t0.z, t0.w, t1.x, t1.y, t1.z, t1.w};
    int ai[8] = {P.a0.x, P.a0.y, P.a0.z, P.a0.w, P.a1.x, P.a1.y, P.a1.z, P.a1.w};
    float e[8];
#pragma unroll
    for (int q = 0; q < 8; ++q) {
      float x = si + tj[q];
      float y = fmaxf(x, 0.2f * x);            // leaky-relu in log2 units
      float ev = __builtin_amdgcn_exp2f(y);
      ev = ai[q] ? ev : 0.f;
      e[q] = ev;
      lsum += ev;
    }
    union { unsigned u[4]; short8 v; } af;
#pragma unroll
    for (int q2 = 0; q2 < 4; ++q2) {
      unsigned r;
      asm("v_cvt_pk_bf16_f32 %0, %1, %2" : "=v"(r) : "v"(e[2 * q2]), "v"(e[2 * q2 + 1]));
      af.u[q2] = r;
    }
    union { uint4 q; short8 v; } b0, b1;
    b0.q = P.fb0; b1.q = P.fb1;
    acc0 = __builtin_amdgcn_mfma_f32_32x32x16_bf16(af.v, b0.v, acc0, 0, 0, 0);
    acc1 = __builtin_amdgcn_mfma_f32_32x32x16_bf16(af.v, b1.v, acc1, 0, 0, 0);
  };

  Pref A, B;
  LOADS(0, A);
  for (int s = 0; s < 62; s += 2) {
    LOADS(s + 1, B);
    COMP(s, A);
    LOADS(s + 2, A);
    COMP(s + 1, B);
  }
  LOADS(63, B);
  COMP(62, A);
  COMP(63, B);

  // ---- epilogue: combine p=0/p=1 partials, normalize, store ----
  float lsum2 = lsum + __shfl_xor(lsum, 32);   // fold kh halves
  float* ep = (float*)lds;                      // [4][32][64] f32 = 32 KB
  float* el = (float*)(lds + 32768);            // [4][32] f32
  __syncthreads();                              // everyone done reading sd
  if (p == 1) {
#pragma unroll
    for (int reg = 0; reg < 16; ++reg) {
      const int row = (reg & 3) + 8 * (reg >> 2) + 4 * kh;
      ep[(h * 32 + row) * 64 + l31]      = acc0[reg];
      ep[(h * 32 + row) * 64 + l31 + 32] = acc1[reg];
    }
    if (lane < 32) el[h * 32 + l31] = lsum2;
  }
  __syncthreads();
  if (p == 0) {
    const float L = lsum2 + el[h * 32 + l31];
    const float rinv = 1.0f / L;
    float* ob = out + ((size_t)(b * 2048 + i0)) * 256 + h * 64;
#pragma unroll
    for (int reg = 0; reg < 16; ++reg) {
      const int row = (reg & 3) + 8 * (reg >> 2) + 4 * kh;
      const float ri = __shfl(rinv, row);
      const float o0 = (acc0[reg] + ep[(h * 32 + row) * 64 + l31]) * ri;
      const float o1 = (acc1[reg] + ep[(h * 32 + row) * 64 + l31 + 32]) * ri;
      ob[(size_t)row * 256 + l31]      = o0;
      ob[(size_t)row * 256 + l31 + 32] = o1;
    }
  }
}

// ---------------------------------------------------------------------------
extern "C" void kernel_launch(void* const* d_in, const int* in_sizes, int n_in,
                              void* d_out, int out_size, void* d_ws, size_t ws_size,
                              hipStream_t stream) {
  const float* X    = (const float*)d_in[0];   // (8,2048,256) f32
  const int*   adj  = (const int*)d_in[1];     // (8,2048,2048) i32
  const float* W    = (const float*)d_in[2];   // (256,256) f32
  const float* bias = (const float*)d_in[3];   // (256,) f32
  const float* a    = (const float*)d_in[4];   // (4,128) f32
  float* out = (float*)d_out;

  unsigned short* ft = (unsigned short*)d_ws;                    // 8 MB bf16
  float* ssrc = (float*)((char*)d_ws + 8388608);                 // 256 KB
  float* sdst = ssrc + 8 * 4 * 2048;                             // 256 KB

  gat_k1<<<dim3(128, 2, 1), 256, 0, stream>>>(X, W, bias, a, ft, ssrc, sdst);
  gat_k2<<<dim3(512, 1, 1), 512, 0, stream>>>(adj, ft, ssrc, sdst, out);
}